// Round 9
// baseline (475.251 us; speedup 1.0000x reference)
//
#include <hip/hip_runtime.h>
#include <cstdint>
#include <cstddef>

typedef unsigned short u16;
typedef __bf16 bf16x8 __attribute__((ext_vector_type(8)));
typedef u16 u16x8 __attribute__((ext_vector_type(8)));
typedef float f32x4 __attribute__((ext_vector_type(4)));

#define N_NODES 100000
#define SAMPLE 25
#define FEAT 128
#define CLASSES 40
#define PLSTR ((size_t)N_NODES * 16)   // u16 elems per 16-feature plane

__device__ __forceinline__ float bf2f(u16 v) {
    return __uint_as_float(((unsigned)v) << 16);
}
__device__ __forceinline__ u16 f2bf(float f) {
    unsigned u = __float_as_uint(f);
    u += 0x7FFFu + ((u >> 16) & 1u);
    return (u16)(u >> 16);
}
__device__ __forceinline__ void split_bf(float x, u16& hi, u16& lo) {
    hi = f2bf(x);
    lo = f2bf(x - bf2f(hi));
}

__device__ __forceinline__ void split8(const float* ap, bf16x8& ah, bf16x8& al) {
    union { u16x8 u; bf16x8 b; } H, L;
    #pragma unroll
    for (int j = 0; j < 8; ++j) {
        u16 h, lo; split_bf(ap[j], h, lo);
        H.u[j] = h; L.u[j] = lo;
    }
    ah = H.b; al = L.b;
}

__device__ __forceinline__ f32x4 mfma_split(bf16x8 ah, bf16x8 al,
                                            bf16x8 bh, bf16x8 bl, f32x4 acc) {
    acc = __builtin_amdgcn_mfma_f32_16x16x32_bf16(ah, bh, acc, 0, 0, 0);
    acc = __builtin_amdgcn_mfma_f32_16x16x32_bf16(al, bh, acc, 0, 0, 0);
    acc = __builtin_amdgcn_mfma_f32_16x16x32_bf16(ah, bl, acc, 0, 0, 0);
    return acc;
}

// ---------------------------------------------------------------------------
// Prep: split fp32 weights into bf16 hi/lo pairs
// ---------------------------------------------------------------------------
__global__ __launch_bounds__(256) void prep_weights(
    const float* __restrict__ W1, const float* __restrict__ W2,
    const float* __restrict__ Wl,
    u16* __restrict__ w1h, u16* __restrict__ w1l,
    u16* __restrict__ w2h, u16* __restrict__ w2l,
    u16* __restrict__ wlh, u16* __restrict__ wll)
{
    const int i = blockIdx.x * 256 + threadIdx.x;
    const int stride = gridDim.x * 256;
    for (int j = i; j < FEAT * FEAT; j += stride) {
        split_bf(W1[j], w1h[j], w1l[j]);
        split_bf(W2[j], w2h[j], w2l[j]);
    }
    for (int j = i; j < CLASSES * FEAT; j += stride) {
        split_bf(Wl[j], wlh[j], wll[j]);
    }
}

#define NPB32 32
#define ZT_STRIDE 136

// ===========================================================================
// PLANE PATH: Z stored plane-major (plane p: node n's 16 feats at
// p*PLSTR + n*16). Gather kernels are plane-phased for L2 residency.
// ===========================================================================

// shared GEMM front: lane fragments from a fp32 row (raw, no relu)
__device__ __forceinline__ void load_afrag_f32(
    const float* __restrict__ row, int lq, bf16x8 (&ah)[4], bf16x8 (&al)[4])
{
    #pragma unroll
    for (int k = 0; k < 4; ++k) {
        f32x4 x0 = *(const f32x4*)(row + k * 32 + lq * 8);
        f32x4 x1 = *(const f32x4*)(row + k * 32 + lq * 8 + 4);
        float tmp[8];
        #pragma unroll
        for (int j = 0; j < 4; ++j) { tmp[j] = x0[j]; tmp[4 + j] = x1[j]; }
        split8(tmp, ah[k], al[k]);
    }
}

// K1: Zp1 = X @ W1^T  (bf16, plane-major out via LDS staging)
__global__ __launch_bounds__(128, 4) void k1_pl(
    const float* __restrict__ X,
    const u16* __restrict__ w1h, const u16* __restrict__ w1l,
    u16* __restrict__ Zp)
{
    __shared__ u16 zt[NPB32][ZT_STRIDE];

    const int t = threadIdx.x;
    const int w  = t >> 6;
    const int l  = t & 63;
    const int lr = l & 15;
    const int lq = l >> 4;
    const int blockStart = blockIdx.x * NPB32;

    bf16x8 ah[4], al[4];
    load_afrag_f32(X + (size_t)(blockStart + w * 16 + lr) * FEAT, lq, ah, al);

    #pragma unroll
    for (int c = 0; c < 8; ++c) {
        f32x4 acc = {0.f, 0.f, 0.f, 0.f};
        #pragma unroll
        for (int k = 0; k < 4; ++k) {
            const size_t off = (size_t)(c * 16 + lr) * FEAT + k * 32 + lq * 8;
            bf16x8 bh = *(const bf16x8*)(w1h + off);
            bf16x8 bl = *(const bf16x8*)(w1l + off);
            acc = mfma_split(ah[k], al[k], bh, bl, acc);
        }
        #pragma unroll
        for (int r = 0; r < 4; ++r)
            zt[w * 16 + lq * 4 + r][c * 16 + lr] = f2bf(acc[r]);
    }
    __syncthreads();

    // plane-major coalesced stores: 512 chunks of 16B
    #pragma unroll
    for (int p = 0; p < 4; ++p) {
        const int idx = p * 128 + t;
        const int plane = idx >> 6;
        const int rem = idx & 63;
        const int row = rem >> 1;
        const int half = rem & 1;
        *(u16x8*)(Zp + (size_t)plane * PLSTR + (size_t)(blockStart + row) * 16 + half * 8) =
            *(const u16x8*)&zt[row][plane * 16 + half * 8];
    }
}

// Gather one plane for 64 nodes: agg[node][plane*16..+16] = relu(mean(Z[nb]))
#define GNPB 64
#define GBLKS 1563   // ceil(100000/64)
__global__ __launch_bounds__(128) void g_hop(
    const u16* __restrict__ Zp, const int* __restrict__ nb,
    float* __restrict__ aggG)
{
    __shared__ int nbs[GNPB * SAMPLE];

    const int t = threadIdx.x;
    const int plane = blockIdx.x / GBLKS;
    const int nblk  = blockIdx.x % GBLKS;
    const int blockStart = nblk * GNPB;

    for (int i = t; i < GNPB * SAMPLE; i += 128) {
        int gi = blockStart * SAMPLE + i;
        if (gi >= N_NODES * SAMPLE) gi = N_NODES * SAMPLE - 1;
        nbs[i] = nb[gi];
    }
    __syncthreads();

    const int nl = t >> 1;
    const int half = t & 1;
    const int node = blockStart + nl;
    const int* myn = &nbs[nl * SAMPLE];
    const u16* base = Zp + (size_t)plane * PLSTR + half * 8;

    float acc[8];
    #pragma unroll
    for (int j = 0; j < 8; ++j) acc[j] = 0.f;

    #pragma unroll 1
    for (int b = 0; b < 5; ++b) {
        u16x8 buf[5];
        #pragma unroll
        for (int s = 0; s < 5; ++s)
            buf[s] = *(const u16x8*)(base + (size_t)myn[b * 5 + s] * 16);
        #pragma unroll
        for (int s = 0; s < 5; ++s) {
            #pragma unroll
            for (int j = 0; j < 8; ++j) acc[j] += bf2f(buf[s][j]);
        }
    }

    if (node < N_NODES) {
        float* dst = aggG + (size_t)node * FEAT + plane * 16 + half * 8;
        f32x4 o0, o1;
        #pragma unroll
        for (int j = 0; j < 4; ++j) {
            float m0 = acc[j] * (1.0f / SAMPLE);
            float m1 = acc[4 + j] * (1.0f / SAMPLE);
            o0[j] = m0 > 0.f ? m0 : 0.f;
            o1[j] = m1 > 0.f ? m1 : 0.f;
        }
        *(f32x4*)dst = o0;
        *(f32x4*)(dst + 4) = o1;
    }
}

// GEMM h @ W^T -> Zp (plane-major bf16, no relu)
__global__ __launch_bounds__(128, 4) void m_mid(
    const float* __restrict__ aggG,
    const u16* __restrict__ wh, const u16* __restrict__ wl,
    u16* __restrict__ Zp)
{
    __shared__ u16 zt[NPB32][ZT_STRIDE];

    const int t = threadIdx.x;
    const int w  = t >> 6;
    const int l  = t & 63;
    const int lr = l & 15;
    const int lq = l >> 4;
    const int blockStart = blockIdx.x * NPB32;

    bf16x8 ah[4], al[4];
    load_afrag_f32(aggG + (size_t)(blockStart + w * 16 + lr) * FEAT, lq, ah, al);

    #pragma unroll
    for (int c = 0; c < 8; ++c) {
        f32x4 acc = {0.f, 0.f, 0.f, 0.f};
        #pragma unroll
        for (int k = 0; k < 4; ++k) {
            const size_t off = (size_t)(c * 16 + lr) * FEAT + k * 32 + lq * 8;
            bf16x8 bh = *(const bf16x8*)(wh + off);
            bf16x8 bl = *(const bf16x8*)(wl + off);
            acc = mfma_split(ah[k], al[k], bh, bl, acc);
        }
        #pragma unroll
        for (int r = 0; r < 4; ++r)
            zt[w * 16 + lq * 4 + r][c * 16 + lr] = f2bf(acc[r]);
    }
    __syncthreads();

    #pragma unroll
    for (int p = 0; p < 4; ++p) {
        const int idx = p * 128 + t;
        const int plane = idx >> 6;
        const int rem = idx & 63;
        const int row = rem >> 1;
        const int half = rem & 1;
        *(u16x8*)(Zp + (size_t)plane * PLSTR + (size_t)(blockStart + row) * 16 + half * 8) =
            *(const u16x8*)&zt[row][plane * 16 + half * 8];
    }
}

// final GEMM h2 @ Wlast^T -> out fp32
__global__ __launch_bounds__(128, 4) void m_last(
    const float* __restrict__ aggG,
    const u16* __restrict__ wh, const u16* __restrict__ wl,
    float* __restrict__ out)
{
    const int t = threadIdx.x;
    const int w  = t >> 6;
    const int l  = t & 63;
    const int lr = l & 15;
    const int lq = l >> 4;
    const int blockStart = blockIdx.x * NPB32;

    bf16x8 ah[4], al[4];
    load_afrag_f32(aggG + (size_t)(blockStart + w * 16 + lr) * FEAT, lq, ah, al);

    #pragma unroll
    for (int c = 0; c < 3; ++c) {
        const int o = c * 16 + lr;
        f32x4 a = {0.f, 0.f, 0.f, 0.f};
        #pragma unroll
        for (int k = 0; k < 4; ++k) {
            bf16x8 bh, bl;
            if (o < CLASSES) {
                const size_t off = (size_t)o * FEAT + k * 32 + lq * 8;
                bh = *(const bf16x8*)(wh + off);
                bl = *(const bf16x8*)(wl + off);
            } else {
                #pragma unroll
                for (int j = 0; j < 8; ++j) { bh[j] = (__bf16)0.f; bl[j] = (__bf16)0.f; }
            }
            a = mfma_split(ah[k], al[k], bh, bl, a);
        }
        if (o < CLASSES) {
            #pragma unroll
            for (int r = 0; r < 4; ++r) {
                const int node = blockStart + w * 16 + lq * 4 + r;
                out[(size_t)node * CLASSES + o] = a[r];
            }
        }
    }
}

// ===========================================================================
// R4 PATH (proven 328.6 µs, row-major Z, ws >= 51.4 MB)
// ===========================================================================
__global__ __launch_bounds__(128, 4) void k1_row(
    const float* __restrict__ X,
    const u16* __restrict__ w1h, const u16* __restrict__ w1l,
    u16* __restrict__ Z1)
{
    __shared__ u16 zt[NPB32][ZT_STRIDE];

    const int t = threadIdx.x;
    const int w  = t >> 6;
    const int l  = t & 63;
    const int lr = l & 15;
    const int lq = l >> 4;
    const int blockStart = blockIdx.x * NPB32;

    bf16x8 ah[4], al[4];
    load_afrag_f32(X + (size_t)(blockStart + w * 16 + lr) * FEAT, lq, ah, al);

    #pragma unroll
    for (int c = 0; c < 8; ++c) {
        f32x4 acc = {0.f, 0.f, 0.f, 0.f};
        #pragma unroll
        for (int k = 0; k < 4; ++k) {
            const size_t off = (size_t)(c * 16 + lr) * FEAT + k * 32 + lq * 8;
            bf16x8 bh = *(const bf16x8*)(w1h + off);
            bf16x8 bl = *(const bf16x8*)(w1l + off);
            acc = mfma_split(ah[k], al[k], bh, bl, acc);
        }
        #pragma unroll
        for (int r = 0; r < 4; ++r)
            zt[w * 16 + lq * 4 + r][c * 16 + lr] = f2bf(acc[r]);
    }
    __syncthreads();

    #pragma unroll
    for (int p = 0; p < 4; ++p) {
        const int idx = p * 128 + t;
        const int row = idx >> 4;
        const int col = (idx & 15) * 8;
        *(u16x8*)(Z1 + (size_t)(blockStart + row) * FEAT + col) =
            *(const u16x8*)&zt[row][col];
    }
}

__global__ __launch_bounds__(128, 3) void k2_r4(
    const u16* __restrict__ Zin, const int* __restrict__ nb,
    const u16* __restrict__ wh, const u16* __restrict__ wl,
    u16* __restrict__ Zout)
{
    __shared__ int nbs[NPB32 * SAMPLE];
    __shared__ float agg[NPB32][132];

    const int t = threadIdx.x;
    const int blockStart = blockIdx.x * NPB32;

    for (int i = t; i < NPB32 * SAMPLE; i += 128)
        nbs[i] = nb[blockStart * SAMPLE + i];
    __syncthreads();

    #pragma unroll 1
    for (int it = 0; it < 4; ++it) {
        const int item = t + it * 128;
        const int nl = item >> 4;
        const int fg = item & 15;
        const int* myn = &nbs[nl * SAMPLE];
        u16x8 buf[SAMPLE];
        #pragma unroll
        for (int s = 0; s < SAMPLE; ++s)
            buf[s] = *(const u16x8*)(Zin + ((size_t)myn[s] << 7) + fg * 8);
        float acc[8];
        #pragma unroll
        for (int j = 0; j < 8; ++j) acc[j] = 0.f;
        #pragma unroll
        for (int s = 0; s < SAMPLE; ++s) {
            #pragma unroll
            for (int j = 0; j < 8; ++j) acc[j] += bf2f(buf[s][j]);
        }
        #pragma unroll
        for (int j = 0; j < 8; ++j) {
            float m = acc[j] * (1.0f / SAMPLE);
            agg[nl][fg * 8 + j] = m > 0.f ? m : 0.f;
        }
    }
    __syncthreads();

    const int w  = t >> 6;
    const int l  = t & 63;
    const int lr = l & 15;
    const int lq = l >> 4;

    bf16x8 ah[4], al[4];
    #pragma unroll
    for (int k = 0; k < 4; ++k)
        split8(&agg[w * 16 + lr][k * 32 + lq * 8], ah[k], al[k]);
    __syncthreads();

    u16* zt = (u16*)agg;

    #pragma unroll
    for (int c = 0; c < 8; ++c) {
        f32x4 acc = {0.f, 0.f, 0.f, 0.f};
        #pragma unroll
        for (int k = 0; k < 4; ++k) {
            const size_t off = (size_t)(c * 16 + lr) * FEAT + k * 32 + lq * 8;
            bf16x8 bh = *(const bf16x8*)(wh + off);
            bf16x8 bl = *(const bf16x8*)(wl + off);
            acc = mfma_split(ah[k], al[k], bh, bl, acc);
        }
        #pragma unroll
        for (int r = 0; r < 4; ++r)
            zt[(size_t)(w * 16 + lq * 4 + r) * ZT_STRIDE + c * 16 + lr] = f2bf(acc[r]);
    }
    __syncthreads();

    #pragma unroll
    for (int p = 0; p < 4; ++p) {
        const int idx = p * 128 + t;
        const int row = idx >> 4;
        const int col = (idx & 15) * 8;
        *(u16x8*)(Zout + (size_t)(blockStart + row) * FEAT + col) =
            *(const u16x8*)&zt[(size_t)row * ZT_STRIDE + col];
    }
}

__global__ __launch_bounds__(128, 3) void k3_r4(
    const u16* __restrict__ Zin, const int* __restrict__ nb,
    const u16* __restrict__ wh, const u16* __restrict__ wl,
    float* __restrict__ out)
{
    __shared__ int nbs[NPB32 * SAMPLE];
    __shared__ float agg[NPB32][132];

    const int t = threadIdx.x;
    const int blockStart = blockIdx.x * NPB32;

    for (int i = t; i < NPB32 * SAMPLE; i += 128)
        nbs[i] = nb[blockStart * SAMPLE + i];
    __syncthreads();

    #pragma unroll 1
    for (int it = 0; it < 4; ++it) {
        const int item = t + it * 128;
        const int nl = item >> 4;
        const int fg = item & 15;
        const int* myn = &nbs[nl * SAMPLE];
        u16x8 buf[SAMPLE];
        #pragma unroll
        for (int s = 0; s < SAMPLE; ++s)
            buf[s] = *(const u16x8*)(Zin + ((size_t)myn[s] << 7) + fg * 8);
        float acc[8];
        #pragma unroll
        for (int j = 0; j < 8; ++j) acc[j] = 0.f;
        #pragma unroll
        for (int s = 0; s < SAMPLE; ++s) {
            #pragma unroll
            for (int j = 0; j < 8; ++j) acc[j] += bf2f(buf[s][j]);
        }
        #pragma unroll
        for (int j = 0; j < 8; ++j) {
            float m = acc[j] * (1.0f / SAMPLE);
            agg[nl][fg * 8 + j] = m > 0.f ? m : 0.f;
        }
    }
    __syncthreads();

    const int w  = t >> 6;
    const int l  = t & 63;
    const int lr = l & 15;
    const int lq = l >> 4;

    bf16x8 ah[4], al[4];
    #pragma unroll
    for (int k = 0; k < 4; ++k)
        split8(&agg[w * 16 + lr][k * 32 + lq * 8], ah[k], al[k]);

    #pragma unroll
    for (int c = 0; c < 3; ++c) {
        const int o = c * 16 + lr;
        f32x4 a = {0.f, 0.f, 0.f, 0.f};
        #pragma unroll
        for (int k = 0; k < 4; ++k) {
            bf16x8 bh, bl;
            if (o < CLASSES) {
                const size_t off = (size_t)o * FEAT + k * 32 + lq * 8;
                bh = *(const bf16x8*)(wh + off);
                bl = *(const bf16x8*)(wl + off);
            } else {
                #pragma unroll
                for (int j = 0; j < 8; ++j) { bh[j] = (__bf16)0.f; bl[j] = (__bf16)0.f; }
            }
            a = mfma_split(ah[k], al[k], bh, bl, a);
        }
        if (o < CLASSES) {
            #pragma unroll
            for (int r = 0; r < 4; ++r) {
                const int node = blockStart + w * 16 + lq * 4 + r;
                out[(size_t)node * CLASSES + o] = a[r];
            }
        }
    }
}

extern "C" void kernel_launch(void* const* d_in, const int* in_sizes, int n_in,
                              void* d_out, int out_size, void* d_ws, size_t ws_size,
                              hipStream_t stream) {
    const float* X  = (const float*)d_in[0];
    const int*   nb = (const int*)d_in[1];
    const float* W1 = (const float*)d_in[2];
    const float* W2 = (const float*)d_in[3];
    const float* Wl = (const float*)d_in[4];
    float* out = (float*)d_out;

    const size_t zelems = (size_t)N_NODES * FEAT;   // 12.8M
    const size_t welems = 4 * (size_t)FEAT * FEAT + 2 * (size_t)CLASSES * FEAT;
    const size_t need_plane = zelems * sizeof(u16) + zelems * sizeof(float)
                            + welems * sizeof(u16);               // ~77.7 MB
    const size_t need_r4 = (2 * zelems + welems) * sizeof(u16);   // ~51.4 MB

    const int gblocks = N_NODES / NPB32;   // 3125, exact

    if (ws_size >= need_plane) {
        // plane-partitioned path
        u16*   Zp   = (u16*)d_ws;                       // 25.6 MB (reused both hops)
        float* aggG = (float*)(Zp + zelems);            // 51.2 MB
        u16*   w1h  = (u16*)(aggG + zelems);
        u16*   w1l  = w1h + FEAT * FEAT;
        u16*   w2h  = w1l + FEAT * FEAT;
        u16*   w2l  = w2h + FEAT * FEAT;
        u16*   wlh  = w2l + FEAT * FEAT;
        u16*   wll  = wlh + CLASSES * FEAT;

        prep_weights<<<64, 256, 0, stream>>>(W1, W2, Wl, w1h, w1l, w2h, w2l, wlh, wll);
        k1_pl<<<gblocks, 128, 0, stream>>>(X, w1h, w1l, Zp);
        g_hop<<<8 * GBLKS, 128, 0, stream>>>(Zp, nb, aggG);       // h1 -> aggG
        m_mid<<<gblocks, 128, 0, stream>>>(aggG, w2h, w2l, Zp);   // Z2 (overwrites Z1)
        g_hop<<<8 * GBLKS, 128, 0, stream>>>(Zp, nb, aggG);       // h2 -> aggG
        m_last<<<gblocks, 128, 0, stream>>>(aggG, wlh, wll, out);
    } else {
        // proven R4 path
        u16* Z1  = (u16*)d_ws;
        u16* Z2  = Z1 + zelems;
        u16* w1h = Z2 + zelems;
        u16* w1l = w1h + FEAT * FEAT;
        u16* w2h = w1l + FEAT * FEAT;
        u16* w2l = w2h + FEAT * FEAT;
        u16* wlh = w2l + FEAT * FEAT;
        u16* wll = wlh + CLASSES * FEAT;

        prep_weights<<<64, 256, 0, stream>>>(W1, W2, Wl, w1h, w1l, w2h, w2l, wlh, wll);
        k1_row<<<gblocks, 128, 0, stream>>>(X, w1h, w1l, Z1);
        k2_r4<<<gblocks, 128, 0, stream>>>(Z1, nb, w2h, w2l, Z2);
        k3_r4<<<gblocks, 128, 0, stream>>>(Z2, nb, wlh, wll, out);
    }
}